// Round 1
// baseline (2767.423 us; speedup 1.0000x reference)
//
#include <hip/hip_runtime.h>
#include <math.h>

#define B_   4096
#define DZ   128
#define DF   2048
#define N2   8192            // 2*B_
#define NL   8191            // 2*B_ - 1

// d_out layout (floats): [loss(1)][logits(8192*8191)][labels(8192)][lids32(8192)][lids512(8192)]
#define OFF_LOGITS 1
#define OFF_LAB  (1 + (size_t)N2 * NL)      // 67100673
#define OFF_L32  (OFF_LAB + N2)             // 67108865
#define OFF_L512 (OFF_L32 + N2)             // 67117057
// D2 scratch overlays d_out[0 .. N2*N2) = [0, 67108864) — disjoint from lids slots.

// ws layout (floats)
#define WS_ZN 0
#define WS_FN ((size_t)N2 * DZ)             // 1048576
#define WS_LP (WS_FN + N2)

// ---------------- row norms of f (||f_i||^2) ----------------
__global__ __launch_bounds__(256) void fnorm_kernel(const float* __restrict__ f0,
                                                    const float* __restrict__ f1,
                                                    float* __restrict__ fn) {
  int r = blockIdx.x;
  const float* row = (r < B_) ? f0 + (size_t)r * DF : f1 + (size_t)(r - B_) * DF;
  float s = 0.f;
  for (int j = threadIdx.x; j < DF; j += 256) { float v = row[j]; s += v * v; }
  for (int off = 32; off; off >>= 1) s += __shfl_down(s, off, 64);
  __shared__ float red[4];
  if ((threadIdx.x & 63) == 0) red[threadIdx.x >> 6] = s;
  __syncthreads();
  if (threadIdx.x == 0) fn[r] = red[0] + red[1] + red[2] + red[3];
}

// ---------------- normalize z rows ----------------
__global__ void znorm_kernel(const float* __restrict__ z0, const float* __restrict__ z1,
                             float* __restrict__ zn) {
  int r = blockIdx.x, t = threadIdx.x;  // 128 threads
  const float* row = (r < B_) ? z0 + (size_t)r * DZ : z1 + (size_t)(r - B_) * DZ;
  float v = row[t];
  float s = v * v;
  for (int off = 32; off; off >>= 1) s += __shfl_down(s, off, 64);
  __shared__ float red[2];
  if ((t & 63) == 0) red[t >> 6] = s;
  __syncthreads();
  float n = sqrtf(red[0] + red[1]);
  zn[(size_t)r * DZ + t] = v / fmaxf(n, 1e-12f);
}

// ---------------- D2 = ||fi||^2 + ||fj||^2 - 2 f fT, upper-tri blocks + mirror ----------------
// 128x128 tile, 256 threads, 8x8 micro-tile. rows m = ty*8+v, cols n = tx*4+(u&3)+64*(u>>2)
__global__ __launch_bounds__(256) void d2_gemm_kernel(const float* __restrict__ f0,
                                                      const float* __restrict__ f1,
                                                      const float* __restrict__ fn,
                                                      float* __restrict__ D2) {
  int bj = blockIdx.x, bi = blockIdx.y;
  if (bi > bj) return;
  const int ib = bi * 128, jb = bj * 128;
  const float* Ab = (ib < B_) ? f0 + (size_t)ib * DF : f1 + (size_t)(ib - B_) * DF;
  const float* Bb = (jb < B_) ? f0 + (size_t)jb * DF : f1 + (size_t)(jb - B_) * DF;

  __shared__ __attribute__((aligned(16))) float As[16][128];
  __shared__ __attribute__((aligned(16))) float Bs[16][128];

  int tid = threadIdx.x;
  int tx = tid & 15, ty = tid >> 4;
  int lrow = tid >> 1;            // 0..127
  int lk   = (tid & 1) * 8;       // 0 or 8 (col offset within 16-wide k-slab)

  float acc[8][8];
#pragma unroll
  for (int i = 0; i < 8; i++)
#pragma unroll
    for (int j = 0; j < 8; j++) acc[i][j] = 0.f;

  for (int k0 = 0; k0 < DF; k0 += 16) {
    float4 a0 = *(const float4*)(Ab + (size_t)lrow * DF + k0 + lk);
    float4 a1 = *(const float4*)(Ab + (size_t)lrow * DF + k0 + lk + 4);
    float4 b0 = *(const float4*)(Bb + (size_t)lrow * DF + k0 + lk);
    float4 b1 = *(const float4*)(Bb + (size_t)lrow * DF + k0 + lk + 4);
    __syncthreads();
    As[lk + 0][lrow] = a0.x; As[lk + 1][lrow] = a0.y; As[lk + 2][lrow] = a0.z; As[lk + 3][lrow] = a0.w;
    As[lk + 4][lrow] = a1.x; As[lk + 5][lrow] = a1.y; As[lk + 6][lrow] = a1.z; As[lk + 7][lrow] = a1.w;
    Bs[lk + 0][lrow] = b0.x; Bs[lk + 1][lrow] = b0.y; Bs[lk + 2][lrow] = b0.z; Bs[lk + 3][lrow] = b0.w;
    Bs[lk + 4][lrow] = b1.x; Bs[lk + 5][lrow] = b1.y; Bs[lk + 6][lrow] = b1.z; Bs[lk + 7][lrow] = b1.w;
    __syncthreads();
#pragma unroll
    for (int kk = 0; kk < 16; kk++) {
      float4 av0 = *(const float4*)&As[kk][ty * 8];
      float4 av1 = *(const float4*)&As[kk][ty * 8 + 4];
      float4 bv0 = *(const float4*)&Bs[kk][tx * 4];
      float4 bv1 = *(const float4*)&Bs[kk][tx * 4 + 64];
      float a_[8] = {av0.x, av0.y, av0.z, av0.w, av1.x, av1.y, av1.z, av1.w};
      float b_[8] = {bv0.x, bv0.y, bv0.z, bv0.w, bv1.x, bv1.y, bv1.z, bv1.w};
#pragma unroll
      for (int v = 0; v < 8; v++)
#pragma unroll
        for (int u = 0; u < 8; u++) acc[v][u] += a_[v] * b_[u];
    }
  }

  float fnj[8];
#pragma unroll
  for (int u = 0; u < 8; u++) fnj[u] = fn[jb + tx * 4 + (u & 3) + (u >> 2) * 64];
#pragma unroll
  for (int v = 0; v < 8; v++) {
    float fni = fn[ib + ty * 8 + v];
#pragma unroll
    for (int u = 0; u < 8; u++)
      acc[v][u] = fmaxf(fni + fnj[u] - 2.f * acc[v][u], 0.f);
  }
  // direct store (rows i, cols j)
#pragma unroll
  for (int v = 0; v < 8; v++) {
    size_t i = ib + ty * 8 + v;
    float4 s0 = make_float4(acc[v][0], acc[v][1], acc[v][2], acc[v][3]);
    float4 s1 = make_float4(acc[v][4], acc[v][5], acc[v][6], acc[v][7]);
    *(float4*)&D2[i * N2 + jb + tx * 4] = s0;
    *(float4*)&D2[i * N2 + jb + tx * 4 + 64] = s1;
  }
  // mirror store (rows j, cols i)
  if (bi != bj) {
#pragma unroll
    for (int u = 0; u < 8; u++) {
      size_t j = jb + tx * 4 + (u & 3) + (u >> 2) * 64;
      float4 m0 = make_float4(acc[0][u], acc[1][u], acc[2][u], acc[3][u]);
      float4 m1 = make_float4(acc[4][u], acc[5][u], acc[6][u], acc[7][u]);
      *(float4*)&D2[j * N2 + ib + ty * 8] = m0;
      *(float4*)&D2[j * N2 + ib + ty * 8 + 4] = m1;
    }
  }
}

// ---------------- per-row 513-smallest + LID ----------------
__global__ __launch_bounds__(256) void select_lid_kernel(const float* __restrict__ D2,
                                                         float* __restrict__ out) {
  int r = blockIdx.x, tid = threadIdx.x;
  const float* row = D2 + (size_t)r * N2;
  unsigned key[32];
#pragma unroll
  for (int j = 0; j < 32; j++) {
    float v = fmaxf(row[tid + j * 256], 0.f);   // clip(d2, 0); nonneg floats: bits are order-preserving
    key[j] = __float_as_uint(v);
  }
  __shared__ int wcnt[32][4];
  __shared__ int pref[256];
  __shared__ unsigned cand[512];
  __shared__ float rr[8];

  // bit-descent: T = max{x : count(key < x) <= 512} = 513th smallest key
  unsigned T = 0;
  for (int b = 30; b >= 0; b--) {
    unsigned t = T | (1u << b);
    int c = 0;
#pragma unroll
    for (int j = 0; j < 32; j++) c += (key[j] < t) ? 1 : 0;
    for (int off = 32; off; off >>= 1) c += __shfl_down(c, off, 64);
    if ((tid & 63) == 0) wcnt[b][tid >> 6] = c;
    __syncthreads();
    int tot = wcnt[b][0] + wcnt[b][1] + wcnt[b][2] + wcnt[b][3];
    if (tot <= 512) T = t;
  }

  // gather strictly-less-than-T candidates (count c0 <= 512)
  int n_t = 0;
#pragma unroll
  for (int j = 0; j < 32; j++) n_t += (key[j] < T) ? 1 : 0;
  pref[tid] = n_t;
  __syncthreads();
  for (int s = 1; s < 256; s <<= 1) {
    int v = (tid >= s) ? pref[tid - s] : 0;
    __syncthreads();
    pref[tid] += v;
    __syncthreads();
  }
  int c0 = pref[255];
  int base = pref[tid] - n_t;
  cand[tid] = 0xFFFFFFFFu;
  cand[tid + 256] = 0xFFFFFFFFu;
  __syncthreads();
  {
    int idx = base;
#pragma unroll
    for (int j = 0; j < 32; j++)
      if (key[j] < T) cand[idx++] = key[j];
  }
  __syncthreads();

  // bitonic sort 512 ascending
  for (int k = 2; k <= 512; k <<= 1) {
    for (int j = k >> 1; j > 0; j >>= 1) {
      int i = ((tid & ~(j - 1)) << 1) | (tid & (j - 1));
      int p = i | j;
      bool up = (i & k) == 0;
      unsigned a = cand[i], b2 = cand[p];
      if ((a > b2) == up) { cand[i] = b2; cand[p] = a; }
      __syncthreads();
    }
  }

  // sorted 513-ascending = cand[0..c0) ++ (513-c0) copies of T; element 0 is the self (dropped)
  float d32  = sqrtf(__uint_as_float(32  < c0 ? cand[32]  : T));
  float d512 = sqrtf(__uint_as_float(512 < c0 ? cand[512] : T));
  int i1 = tid + 1, i2 = tid + 257;
  float di1 = sqrtf(__uint_as_float(i1 < c0 ? cand[i1] : T));
  float di2 = sqrtf(__uint_as_float(i2 < c0 ? cand[i2] : T));
  float s32 = (i1 <= 32) ? logf(di1 / d32 + 1e-12f) : 0.f;
  float s512 = logf(di1 / d512 + 1e-12f) + logf(di2 / d512 + 1e-12f);
  for (int off = 32; off; off >>= 1) {
    s32 += __shfl_down(s32, off, 64);
    s512 += __shfl_down(s512, off, 64);
  }
  if ((tid & 63) == 0) { rr[tid >> 6] = s32; rr[4 + (tid >> 6)] = s512; }
  __syncthreads();
  if (tid == 0) {
    float S32 = rr[0] + rr[1] + rr[2] + rr[3];
    float S512 = rr[4] + rr[5] + rr[6] + rr[7];
    out[OFF_L32 + r] = -32.f / S32;
    out[OFF_L512 + r] = -512.f / S512;
  }
}

// ---------------- logits = reshuffled z-gram / T ----------------
__global__ __launch_bounds__(256) void zgram_logits_kernel(const float* __restrict__ zn,
                                                           float* __restrict__ out) {
  int bj = blockIdx.x, bi = blockIdx.y;
  const int ib = bi * 128, jb = bj * 128;
  const float* Ab = zn + (size_t)ib * DZ;
  const float* Bb = zn + (size_t)jb * DZ;

  __shared__ __attribute__((aligned(16))) float As[16][128];
  __shared__ __attribute__((aligned(16))) float Bs[16][128];

  int tid = threadIdx.x;
  int tx = tid & 15, ty = tid >> 4;
  int lrow = tid >> 1;
  int lk = (tid & 1) * 8;

  float acc[8][8];
#pragma unroll
  for (int i = 0; i < 8; i++)
#pragma unroll
    for (int j = 0; j < 8; j++) acc[i][j] = 0.f;

  for (int k0 = 0; k0 < DZ; k0 += 16) {
    float4 a0 = *(const float4*)(Ab + (size_t)lrow * DZ + k0 + lk);
    float4 a1 = *(const float4*)(Ab + (size_t)lrow * DZ + k0 + lk + 4);
    float4 b0 = *(const float4*)(Bb + (size_t)lrow * DZ + k0 + lk);
    float4 b1 = *(const float4*)(Bb + (size_t)lrow * DZ + k0 + lk + 4);
    __syncthreads();
    As[lk + 0][lrow] = a0.x; As[lk + 1][lrow] = a0.y; As[lk + 2][lrow] = a0.z; As[lk + 3][lrow] = a0.w;
    As[lk + 4][lrow] = a1.x; As[lk + 5][lrow] = a1.y; As[lk + 6][lrow] = a1.z; As[lk + 7][lrow] = a1.w;
    Bs[lk + 0][lrow] = b0.x; Bs[lk + 1][lrow] = b0.y; Bs[lk + 2][lrow] = b0.z; Bs[lk + 3][lrow] = b0.w;
    Bs[lk + 4][lrow] = b1.x; Bs[lk + 5][lrow] = b1.y; Bs[lk + 6][lrow] = b1.z; Bs[lk + 7][lrow] = b1.w;
    __syncthreads();
#pragma unroll
    for (int kk = 0; kk < 16; kk++) {
      float4 av0 = *(const float4*)&As[kk][ty * 8];
      float4 av1 = *(const float4*)&As[kk][ty * 8 + 4];
      float4 bv0 = *(const float4*)&Bs[kk][tx * 4];
      float4 bv1 = *(const float4*)&Bs[kk][tx * 4 + 64];
      float a_[8] = {av0.x, av0.y, av0.z, av0.w, av1.x, av1.y, av1.z, av1.w};
      float b_[8] = {bv0.x, bv0.y, bv0.z, bv0.w, bv1.x, bv1.y, bv1.z, bv1.w};
#pragma unroll
      for (int v = 0; v < 8; v++)
#pragma unroll
        for (int u = 0; u < 8; u++) acc[v][u] += a_[v] * b_[u];
    }
  }

#pragma unroll
  for (int v = 0; v < 8; v++) {
    int rrow = ib + ty * 8 + v;
#pragma unroll
    for (int u = 0; u < 8; u++) {
      int c = jb + tx * 4 + (u & 3) + (u >> 2) * 64;
      if (c == rrow) continue;
      float lg = 2.f * acc[v][u];  // /TEMPERATURE(0.5)
      int col;
      if (rrow < B_) col = (c >= B_) ? (c - B_) : (B_ + c - (c > rrow ? 1 : 0));
      else           col = (c < B_) ? c : (c - (c > rrow ? 1 : 0));
      out[OFF_LOGITS + (size_t)rrow * NL + col] = lg;
    }
  }
}

// ---------------- labels ----------------
__global__ void labels_kernel(float* __restrict__ out) {
  int i = blockIdx.x * 256 + threadIdx.x;
  if (i < N2) out[OFF_LAB + i] = (float)(i & (B_ - 1));
}

// ---------------- per-row loss ----------------
__global__ __launch_bounds__(256) void loss_row_kernel(const float* __restrict__ out,
                                                       float* __restrict__ lossp) {
  int r = blockIdx.x, tid = threadIdx.x;
  const float* row = out + OFF_LOGITS + (size_t)r * NL;
  __shared__ __attribute__((aligned(16))) float buf[NL];
  __shared__ float red[4];
  float m = -1e30f;
  for (int j = tid; j < NL; j += 256) { float v = row[j]; buf[j] = v; m = fmaxf(m, v); }
  for (int off = 32; off; off >>= 1) m = fmaxf(m, __shfl_down(m, off, 64));
  if ((tid & 63) == 0) red[tid >> 6] = m;
  __syncthreads();
  m = fmaxf(fmaxf(red[0], red[1]), fmaxf(red[2], red[3]));
  float s = 0.f;
  for (int j = tid; j < NL; j += 256) s += expf(buf[j] - m);
  for (int off = 32; off; off >>= 1) s += __shfl_down(s, off, 64);
  __syncthreads();
  if ((tid & 63) == 0) red[tid >> 6] = s;
  __syncthreads();
  if (tid == 0) {
    float S = red[0] + red[1] + red[2] + red[3];
    lossp[r] = m + logf(S) - buf[r & (B_ - 1)];
  }
}

// ---------------- final mean ----------------
__global__ void finalize_kernel(const float* __restrict__ lossp, float* __restrict__ out) {
  int tid = threadIdx.x;
  float s = 0.f;
  for (int j = tid; j < N2; j += 256) s += lossp[j];
  for (int off = 32; off; off >>= 1) s += __shfl_down(s, off, 64);
  __shared__ float red[4];
  if ((tid & 63) == 0) red[tid >> 6] = s;
  __syncthreads();
  if (tid == 0) out[0] = (red[0] + red[1] + red[2] + red[3]) / (float)N2;
}

extern "C" void kernel_launch(void* const* d_in, const int* in_sizes, int n_in,
                              void* d_out, int out_size, void* d_ws, size_t ws_size,
                              hipStream_t stream) {
  const float* z0 = (const float*)d_in[0];
  const float* z1 = (const float*)d_in[1];
  const float* f0 = (const float*)d_in[2];
  const float* f1 = (const float*)d_in[3];
  float* out = (float*)d_out;
  float* ws = (float*)d_ws;
  float* zn = ws + WS_ZN;
  float* fn = ws + WS_FN;
  float* lp = ws + WS_LP;
  float* D2 = out;  // scratch overlay on d_out[0 .. N2*N2)

  fnorm_kernel<<<N2, 256, 0, stream>>>(f0, f1, fn);
  znorm_kernel<<<N2, 128, 0, stream>>>(z0, z1, zn);
  dim3 g(64, 64);
  d2_gemm_kernel<<<g, 256, 0, stream>>>(f0, f1, fn, D2);
  select_lid_kernel<<<N2, 256, 0, stream>>>(D2, out);       // lids -> final slots (past D2)
  zgram_logits_kernel<<<g, 256, 0, stream>>>(zn, out);      // overwrites D2 scratch with logits
  labels_kernel<<<(N2 + 255) / 256, 256, 0, stream>>>(out);
  loss_row_kernel<<<N2, 256, 0, stream>>>(out, lp);
  finalize_kernel<<<1, 256, 0, stream>>>(lp, out);
}

// Round 2
// 1532.770 us; speedup vs baseline: 1.8055x; 1.8055x over previous
//
#include <hip/hip_runtime.h>
#include <math.h>

#define B_   4096
#define DZ   128
#define DF   2048
#define N2   8192            // 2*B_
#define NL   8191            // 2*B_ - 1

// d_out layout (floats): [loss(1)][logits(8192*8191)][labels(8192)][lids32(8192)][lids512(8192)]
#define OFF_LOGITS 1
#define OFF_LAB  (1 + (size_t)N2 * NL)      // 67100673
#define OFF_L32  (OFF_LAB + N2)             // 67108865
#define OFF_L512 (OFF_L32 + N2)             // 67117057
// D2 scratch overlays d_out[0 .. N2*N2) = [0, 67108864) — disjoint from lids slots.

// ws layout (floats)
#define WS_ZN 0
#define WS_FN ((size_t)N2 * DZ)             // 1048576
#define WS_LP (WS_FN + N2)

typedef __attribute__((ext_vector_type(8))) __bf16 bf16x8;
typedef __attribute__((ext_vector_type(8))) unsigned short ushort8;
typedef __attribute__((ext_vector_type(4))) float f32x4;

// round-to-nearest-even fp32 -> bf16 bits (inputs are finite Gaussians; no NaN path needed)
__device__ __forceinline__ unsigned short f2bf(float f) {
  unsigned u = __float_as_uint(f);
  return (unsigned short)((u + 0x7FFFu + ((u >> 16) & 1u)) >> 16);
}
__device__ __forceinline__ float bf2f(unsigned short h) {
  return __uint_as_float(((unsigned)h) << 16);
}

// ---------------- row norms of f (||f_i||^2) ----------------
__global__ __launch_bounds__(256) void fnorm_kernel(const float* __restrict__ f0,
                                                    const float* __restrict__ f1,
                                                    float* __restrict__ fn) {
  int r = blockIdx.x;
  const float* row = (r < B_) ? f0 + (size_t)r * DF : f1 + (size_t)(r - B_) * DF;
  float s = 0.f;
  for (int j = threadIdx.x; j < DF; j += 256) { float v = row[j]; s += v * v; }
  for (int off = 32; off; off >>= 1) s += __shfl_down(s, off, 64);
  __shared__ float red[4];
  if ((threadIdx.x & 63) == 0) red[threadIdx.x >> 6] = s;
  __syncthreads();
  if (threadIdx.x == 0) fn[r] = red[0] + red[1] + red[2] + red[3];
}

// ---------------- normalize z rows ----------------
__global__ void znorm_kernel(const float* __restrict__ z0, const float* __restrict__ z1,
                             float* __restrict__ zn) {
  int r = blockIdx.x, t = threadIdx.x;  // 128 threads
  const float* row = (r < B_) ? z0 + (size_t)r * DZ : z1 + (size_t)(r - B_) * DZ;
  float v = row[t];
  float s = v * v;
  for (int off = 32; off; off >>= 1) s += __shfl_down(s, off, 64);
  __shared__ float red[2];
  if ((t & 63) == 0) red[t >> 6] = s;
  __syncthreads();
  float n = sqrtf(red[0] + red[1]);
  zn[(size_t)r * DZ + t] = v / fmaxf(n, 1e-12f);
}

// ---------------- D2 via bf16 hi/lo split MFMA ----------------
// 128x128 tile, 4 waves, each wave a 64x64 quadrant of 4x4 16x16 MFMA tiles.
// Per 32-wide fp32 k-slab: stage {Ahi,Alo,Bhi,Blo} once, 3 MFMA passes
// (hi*hi + hi*lo + lo*hi); lo*lo dropped (~2^-18 relative).
#define LSTR 40   // padded LDS row stride in shorts (80 B): 2-way bank alias = free
__global__ __launch_bounds__(256) void d2_gemm_mfma_kernel(const float* __restrict__ f0,
                                                           const float* __restrict__ f1,
                                                           const float* __restrict__ fn,
                                                           float* __restrict__ D2) {
  int bj = blockIdx.x, bi = blockIdx.y;
  if (bi > bj) return;
  const int ib = bi * 128, jb = bj * 128;
  const float* Ab = (ib < B_) ? f0 + (size_t)ib * DF : f1 + (size_t)(ib - B_) * DF;
  const float* Bb = (jb < B_) ? f0 + (size_t)jb * DF : f1 + (size_t)(jb - B_) * DF;

  __shared__ __attribute__((aligned(16))) unsigned short Ah[128 * LSTR];
  __shared__ __attribute__((aligned(16))) unsigned short Al[128 * LSTR];
  __shared__ __attribute__((aligned(16))) unsigned short Bh[128 * LSTR];
  __shared__ __attribute__((aligned(16))) unsigned short Bl[128 * LSTR];

  const int tid = threadIdx.x;
  const int lane = tid & 63;
  const int wave = tid >> 6;
  const int wr = (wave >> 1) * 64;     // quadrant row base within tile
  const int wc = (wave & 1) * 64;      // quadrant col base within tile
  const int m  = lane & 15;            // frag row/col within 16
  const int kg = lane >> 4;            // k-group (0..3) -> k = kg*8 + j

  const int lrow = tid >> 1;           // staging row 0..127
  const int lhalf = tid & 1;           // staging k-half (0/1 -> +0/+16 floats)
  const float* arow = Ab + (size_t)lrow * DF + lhalf * 16;
  const float* brow = Bb + (size_t)lrow * DF + lhalf * 16;
  const int wbase = lrow * LSTR + lhalf * 16;   // LDS short offset for this thread's 16 elems

  f32x4 acc[4][4];
#pragma unroll
  for (int i = 0; i < 4; i++)
#pragma unroll
    for (int j = 0; j < 4; j++) acc[i][j] = (f32x4)0.f;

  for (int k0 = 0; k0 < DF; k0 += 32) {
    float av[16], bv[16];
#pragma unroll
    for (int q = 0; q < 4; q++) {
      float4 t = *(const float4*)(arow + k0 + q * 4);
      av[q * 4 + 0] = t.x; av[q * 4 + 1] = t.y; av[q * 4 + 2] = t.z; av[q * 4 + 3] = t.w;
    }
#pragma unroll
    for (int q = 0; q < 4; q++) {
      float4 t = *(const float4*)(brow + k0 + q * 4);
      bv[q * 4 + 0] = t.x; bv[q * 4 + 1] = t.y; bv[q * 4 + 2] = t.z; bv[q * 4 + 3] = t.w;
    }

    __syncthreads();  // previous slab's frag reads complete

    ushort8 ah0, ah1, al0, al1, bh0, bh1, bl0, bl1;
#pragma unroll
    for (int j = 0; j < 8; j++) {
      unsigned short h = f2bf(av[j]);     ah0[j] = h; al0[j] = f2bf(av[j] - bf2f(h));
      unsigned short h2 = f2bf(av[j + 8]); ah1[j] = h2; al1[j] = f2bf(av[j + 8] - bf2f(h2));
      unsigned short h3 = f2bf(bv[j]);     bh0[j] = h3; bl0[j] = f2bf(bv[j] - bf2f(h3));
      unsigned short h4 = f2bf(bv[j + 8]); bh1[j] = h4; bl1[j] = f2bf(bv[j + 8] - bf2f(h4));
    }
    *(ushort8*)&Ah[wbase] = ah0;     *(ushort8*)&Ah[wbase + 8] = ah1;
    *(ushort8*)&Al[wbase] = al0;     *(ushort8*)&Al[wbase + 8] = al1;
    *(ushort8*)&Bh[wbase] = bh0;     *(ushort8*)&Bh[wbase + 8] = bh1;
    *(ushort8*)&Bl[wbase] = bl0;     *(ushort8*)&Bl[wbase + 8] = bl1;

    __syncthreads();

    bf16x8 a_h[4], a_l[4], b_h[4], b_l[4];
#pragma unroll
    for (int t4 = 0; t4 < 4; t4++) {
      int aoff = (wr + t4 * 16 + m) * LSTR + kg * 8;
      int boff = (wc + t4 * 16 + m) * LSTR + kg * 8;
      a_h[t4] = *(const bf16x8*)&Ah[aoff];
      a_l[t4] = *(const bf16x8*)&Al[aoff];
      b_h[t4] = *(const bf16x8*)&Bh[boff];
      b_l[t4] = *(const bf16x8*)&Bl[boff];
    }
#pragma unroll
    for (int ti = 0; ti < 4; ti++)
#pragma unroll
      for (int tj = 0; tj < 4; tj++) {
        acc[ti][tj] = __builtin_amdgcn_mfma_f32_16x16x32_bf16(a_h[ti], b_h[tj], acc[ti][tj], 0, 0, 0);
        acc[ti][tj] = __builtin_amdgcn_mfma_f32_16x16x32_bf16(a_h[ti], b_l[tj], acc[ti][tj], 0, 0, 0);
        acc[ti][tj] = __builtin_amdgcn_mfma_f32_16x16x32_bf16(a_l[ti], b_h[tj], acc[ti][tj], 0, 0, 0);
      }
  }

  // epilogue: D2[i][j] = max(fn[i]+fn[j]-2*dot, 0); direct + mirror stores
  // C/D layout: col = lane&15, row = (lane>>4)*4 + reg
#pragma unroll
  for (int ti = 0; ti < 4; ti++) {
    int irow0 = ib + wr + ti * 16 + kg * 4;
    float4 fni = *(const float4*)&fn[irow0];
    float fniv[4] = {fni.x, fni.y, fni.z, fni.w};
#pragma unroll
    for (int tj = 0; tj < 4; tj++) {
      int jg = jb + wc + tj * 16 + m;
      float fnj = fn[jg];
      float val[4];
#pragma unroll
      for (int r = 0; r < 4; r++)
        val[r] = fmaxf(fniv[r] + fnj - 2.f * acc[ti][tj][r], 0.f);
#pragma unroll
      for (int r = 0; r < 4; r++)
        D2[(size_t)(irow0 + r) * N2 + jg] = val[r];
      if (bi != bj)
        *(float4*)&D2[(size_t)jg * N2 + irow0] = make_float4(val[0], val[1], val[2], val[3]);
    }
  }
}

// ---------------- per-row 513-smallest + LID ----------------
__global__ __launch_bounds__(256) void select_lid_kernel(const float* __restrict__ D2,
                                                         float* __restrict__ out) {
  int r = blockIdx.x, tid = threadIdx.x;
  const float* row = D2 + (size_t)r * N2;
  unsigned key[32];
#pragma unroll
  for (int j = 0; j < 32; j++) {
    float v = fmaxf(row[tid + j * 256], 0.f);   // clip(d2, 0); nonneg floats: bits are order-preserving
    key[j] = __float_as_uint(v);
  }
  __shared__ int wcnt[32][4];
  __shared__ int pref[256];
  __shared__ unsigned cand[512];
  __shared__ float rr[8];

  // bit-descent: T = max{x : count(key < x) <= 512} = 513th smallest key
  unsigned T = 0;
  for (int b = 30; b >= 0; b--) {
    unsigned t = T | (1u << b);
    int c = 0;
#pragma unroll
    for (int j = 0; j < 32; j++) c += (key[j] < t) ? 1 : 0;
    for (int off = 32; off; off >>= 1) c += __shfl_down(c, off, 64);
    if ((tid & 63) == 0) wcnt[b][tid >> 6] = c;
    __syncthreads();
    int tot = wcnt[b][0] + wcnt[b][1] + wcnt[b][2] + wcnt[b][3];
    if (tot <= 512) T = t;
  }

  // gather strictly-less-than-T candidates (count c0 <= 512)
  int n_t = 0;
#pragma unroll
  for (int j = 0; j < 32; j++) n_t += (key[j] < T) ? 1 : 0;
  pref[tid] = n_t;
  __syncthreads();
  for (int s = 1; s < 256; s <<= 1) {
    int v = (tid >= s) ? pref[tid - s] : 0;
    __syncthreads();
    pref[tid] += v;
    __syncthreads();
  }
  int c0 = pref[255];
  int base = pref[tid] - n_t;
  cand[tid] = 0xFFFFFFFFu;
  cand[tid + 256] = 0xFFFFFFFFu;
  __syncthreads();
  {
    int idx = base;
#pragma unroll
    for (int j = 0; j < 32; j++)
      if (key[j] < T) cand[idx++] = key[j];
  }
  __syncthreads();

  // bitonic sort 512 ascending
  for (int k = 2; k <= 512; k <<= 1) {
    for (int j = k >> 1; j > 0; j >>= 1) {
      int i = ((tid & ~(j - 1)) << 1) | (tid & (j - 1));
      int p = i | j;
      bool up = (i & k) == 0;
      unsigned a = cand[i], b2 = cand[p];
      if ((a > b2) == up) { cand[i] = b2; cand[p] = a; }
      __syncthreads();
    }
  }

  // sorted 513-ascending = cand[0..c0) ++ (513-c0) copies of T; element 0 is the self (dropped)
  float d32  = sqrtf(__uint_as_float(32  < c0 ? cand[32]  : T));
  float d512 = sqrtf(__uint_as_float(512 < c0 ? cand[512] : T));
  int i1 = tid + 1, i2 = tid + 257;
  float di1 = sqrtf(__uint_as_float(i1 < c0 ? cand[i1] : T));
  float di2 = sqrtf(__uint_as_float(i2 < c0 ? cand[i2] : T));
  float s32 = (i1 <= 32) ? logf(di1 / d32 + 1e-12f) : 0.f;
  float s512 = logf(di1 / d512 + 1e-12f) + logf(di2 / d512 + 1e-12f);
  for (int off = 32; off; off >>= 1) {
    s32 += __shfl_down(s32, off, 64);
    s512 += __shfl_down(s512, off, 64);
  }
  if ((tid & 63) == 0) { rr[tid >> 6] = s32; rr[4 + (tid >> 6)] = s512; }
  __syncthreads();
  if (tid == 0) {
    float S32 = rr[0] + rr[1] + rr[2] + rr[3];
    float S512 = rr[4] + rr[5] + rr[6] + rr[7];
    out[OFF_L32 + r] = -32.f / S32;
    out[OFF_L512 + r] = -512.f / S512;
  }
}

// ---------------- logits = reshuffled z-gram / T ----------------
__global__ __launch_bounds__(256) void zgram_logits_kernel(const float* __restrict__ zn,
                                                           float* __restrict__ out) {
  int bj = blockIdx.x, bi = blockIdx.y;
  const int ib = bi * 128, jb = bj * 128;
  const float* Ab = zn + (size_t)ib * DZ;
  const float* Bb = zn + (size_t)jb * DZ;

  __shared__ __attribute__((aligned(16))) float As[16][128];
  __shared__ __attribute__((aligned(16))) float Bs[16][128];

  int tid = threadIdx.x;
  int tx = tid & 15, ty = tid >> 4;
  int lrow = tid >> 1;
  int lk = (tid & 1) * 8;

  float acc[8][8];
#pragma unroll
  for (int i = 0; i < 8; i++)
#pragma unroll
    for (int j = 0; j < 8; j++) acc[i][j] = 0.f;

  for (int k0 = 0; k0 < DZ; k0 += 16) {
    float4 a0 = *(const float4*)(Ab + (size_t)lrow * DZ + k0 + lk);
    float4 a1 = *(const float4*)(Ab + (size_t)lrow * DZ + k0 + lk + 4);
    float4 b0 = *(const float4*)(Bb + (size_t)lrow * DZ + k0 + lk);
    float4 b1 = *(const float4*)(Bb + (size_t)lrow * DZ + k0 + lk + 4);
    __syncthreads();
    As[lk + 0][lrow] = a0.x; As[lk + 1][lrow] = a0.y; As[lk + 2][lrow] = a0.z; As[lk + 3][lrow] = a0.w;
    As[lk + 4][lrow] = a1.x; As[lk + 5][lrow] = a1.y; As[lk + 6][lrow] = a1.z; As[lk + 7][lrow] = a1.w;
    Bs[lk + 0][lrow] = b0.x; Bs[lk + 1][lrow] = b0.y; Bs[lk + 2][lrow] = b0.z; Bs[lk + 3][lrow] = b0.w;
    Bs[lk + 4][lrow] = b1.x; Bs[lk + 5][lrow] = b1.y; Bs[lk + 6][lrow] = b1.z; Bs[lk + 7][lrow] = b1.w;
    __syncthreads();
#pragma unroll
    for (int kk = 0; kk < 16; kk++) {
      float4 av0 = *(const float4*)&As[kk][ty * 8];
      float4 av1 = *(const float4*)&As[kk][ty * 8 + 4];
      float4 bv0 = *(const float4*)&Bs[kk][tx * 4];
      float4 bv1 = *(const float4*)&Bs[kk][tx * 4 + 64];
      float a_[8] = {av0.x, av0.y, av0.z, av0.w, av1.x, av1.y, av1.z, av1.w};
      float b_[8] = {bv0.x, bv0.y, bv0.z, bv0.w, bv1.x, bv1.y, bv1.z, bv1.w};
#pragma unroll
      for (int v = 0; v < 8; v++)
#pragma unroll
        for (int u = 0; u < 8; u++) acc[v][u] += a_[v] * b_[u];
    }
  }

#pragma unroll
  for (int v = 0; v < 8; v++) {
    int rrow = ib + ty * 8 + v;
#pragma unroll
    for (int u = 0; u < 8; u++) {
      int c = jb + tx * 4 + (u & 3) + (u >> 2) * 64;
      if (c == rrow) continue;
      float lg = 2.f * acc[v][u];  // /TEMPERATURE(0.5)
      int col;
      if (rrow < B_) col = (c >= B_) ? (c - B_) : (B_ + c - (c > rrow ? 1 : 0));
      else           col = (c < B_) ? c : (c - (c > rrow ? 1 : 0));
      out[OFF_LOGITS + (size_t)rrow * NL + col] = lg;
    }
  }
}

// ---------------- labels ----------------
__global__ void labels_kernel(float* __restrict__ out) {
  int i = blockIdx.x * 256 + threadIdx.x;
  if (i < N2) out[OFF_LAB + i] = (float)(i & (B_ - 1));
}

// ---------------- per-row loss ----------------
__global__ __launch_bounds__(256) void loss_row_kernel(const float* __restrict__ out,
                                                       float* __restrict__ lossp) {
  int r = blockIdx.x, tid = threadIdx.x;
  const float* row = out + OFF_LOGITS + (size_t)r * NL;
  __shared__ __attribute__((aligned(16))) float buf[NL];
  __shared__ float red[4];
  float m = -1e30f;
  for (int j = tid; j < NL; j += 256) { float v = row[j]; buf[j] = v; m = fmaxf(m, v); }
  for (int off = 32; off; off >>= 1) m = fmaxf(m, __shfl_down(m, off, 64));
  if ((tid & 63) == 0) red[tid >> 6] = m;
  __syncthreads();
  m = fmaxf(fmaxf(red[0], red[1]), fmaxf(red[2], red[3]));
  float s = 0.f;
  for (int j = tid; j < NL; j += 256) s += expf(buf[j] - m);
  for (int off = 32; off; off >>= 1) s += __shfl_down(s, off, 64);
  __syncthreads();
  if ((tid & 63) == 0) red[tid >> 6] = s;
  __syncthreads();
  if (tid == 0) {
    float S = red[0] + red[1] + red[2] + red[3];
    lossp[r] = m + logf(S) - buf[r & (B_ - 1)];
  }
}

// ---------------- final mean ----------------
__global__ void finalize_kernel(const float* __restrict__ lossp, float* __restrict__ out) {
  int tid = threadIdx.x;
  float s = 0.f;
  for (int j = tid; j < N2; j += 256) s += lossp[j];
  for (int off = 32; off; off >>= 1) s += __shfl_down(s, off, 64);
  __shared__ float red[4];
  if ((tid & 63) == 0) red[tid >> 6] = s;
  __syncthreads();
  if (tid == 0) out[0] = (red[0] + red[1] + red[2] + red[3]) / (float)N2;
}

extern "C" void kernel_launch(void* const* d_in, const int* in_sizes, int n_in,
                              void* d_out, int out_size, void* d_ws, size_t ws_size,
                              hipStream_t stream) {
  const float* z0 = (const float*)d_in[0];
  const float* z1 = (const float*)d_in[1];
  const float* f0 = (const float*)d_in[2];
  const float* f1 = (const float*)d_in[3];
  float* out = (float*)d_out;
  float* ws = (float*)d_ws;
  float* zn = ws + WS_ZN;
  float* fn = ws + WS_FN;
  float* lp = ws + WS_LP;
  float* D2 = out;  // scratch overlay on d_out[0 .. N2*N2)

  fnorm_kernel<<<N2, 256, 0, stream>>>(f0, f1, fn);
  znorm_kernel<<<N2, 128, 0, stream>>>(z0, z1, zn);
  dim3 g(64, 64);
  d2_gemm_mfma_kernel<<<g, 256, 0, stream>>>(f0, f1, fn, D2);
  select_lid_kernel<<<N2, 256, 0, stream>>>(D2, out);       // lids -> final slots (past D2)
  zgram_logits_kernel<<<g, 256, 0, stream>>>(zn, out);      // overwrites D2 scratch with logits
  labels_kernel<<<(N2 + 255) / 256, 256, 0, stream>>>(out);
  loss_row_kernel<<<N2, 256, 0, stream>>>(out, lp);
  finalize_kernel<<<1, 256, 0, stream>>>(lp, out);
}